// Round 9
// baseline (279.117 us; speedup 1.0000x reference)
//
#include <hip/hip_runtime.h>
#include <hip/hip_bf16.h>
#include <stdint.h>

#define NBATCH 65536
#define LSEQ   64

typedef __attribute__((ext_vector_type(8))) _Float16 half8;
typedef __attribute__((ext_vector_type(2))) __fp16  fp16x2; // builtin cvt_pkrtz return type
typedef __attribute__((ext_vector_type(4))) float f32x4;
typedef __attribute__((ext_vector_type(3), aligned(4))) float f32x3u; // 12B store, 4B-aligned
typedef __attribute__((ext_vector_type(4))) int   i32x4;

#define LOG2E 1.44269504088896341f

// relu + pack two f32 -> one dword of two f16 (RTZ)
static __device__ __forceinline__ int relu_pk_f16(float x, float y){
    union { fp16x2 h; int i; } u;
    u.h = __builtin_amdgcn_cvt_pkrtz(fmaxf(x, 0.f), fmaxf(y, 0.f));
    return u.i;
}

// 1 wave = 16 samples. Layer1 folded into f16 LDS table + packed-f16 carry FMA.
// Layers 2+3 on MFMA 16x16x32 f16, fp32 accumulate. Block = 4 waves.
// W2 rows PERMUTED so MFMA2's C-layout directly yields the layer-3 B-frag.
//
// THIS ROUND: carry WITHOUT ds_bpermute. Layer-3 row map per quad q:
//   rows 4q..4q+2 = payload {q0:[d0,d1,d2] q1:[d3,d4,d5] q2:[d6,d7,d8]
//   q3:[d9,c0,c1]}, row 4q+3 = DIFF = (Wc0-Wc1)*log2e (replicated).
// Every lane gets z = (c0-c1)*log2e in acc3[3] locally; carry =
// 1/(1+2^-z) is 3 local VALU ops — the ~120cy LDS bpermute round-trip
// leaves the 64-step serial carry chain entirely.

struct StepCtx {
    half8 dcr0, dcr1, w2f00, w2f01, w2f10, w2f11, w3f;
    f32x4 bias2a, bias2b, bias3;
    const _Float16* Pab;
    int q;
};

// One step: h1 from pc0/pc1, prefetch row for byte ib into pn0/pn1, MFMA x5, carry.
static __device__ __forceinline__ f32x4 step_fn(const StepCtx& C, float& carry,
                                                const half8& pc0, const half8& pc1,
                                                half8& pn0, half8& pn1, int ib)
{
    _Float16 ch = (_Float16)carry;
    half8 c8 = {ch,ch,ch,ch,ch,ch,ch,ch};
    half8 z  = {};
    half8 h10 = __builtin_elementwise_max(pc0 + c8*C.dcr0, z);
    half8 h11 = __builtin_elementwise_max(pc1 + c8*C.dcr1, z);

    const _Float16* rn = C.Pab + (ib & 255)*72 + C.q*8;
    pn0 = *(const half8*)rn;
    pn1 = *(const half8*)(rn + 32);

    f32x4 acc2a = C.bias2a, acc2b = C.bias2b;
    acc2a = __builtin_amdgcn_mfma_f32_16x16x32_f16(C.w2f00, h10, acc2a, 0,0,0);
    acc2a = __builtin_amdgcn_mfma_f32_16x16x32_f16(C.w2f01, h11, acc2a, 0,0,0);
    acc2b = __builtin_amdgcn_mfma_f32_16x16x32_f16(C.w2f10, h10, acc2b, 0,0,0);
    acc2b = __builtin_amdgcn_mfma_f32_16x16x32_f16(C.w2f11, h11, acc2b, 0,0,0);

    union { i32x4 d; half8 v; } uh2;
    uh2.d = i32x4{ relu_pk_f16(acc2a[0], acc2a[1]), relu_pk_f16(acc2a[2], acc2a[3]),
                   relu_pk_f16(acc2b[0], acc2b[1]), relu_pk_f16(acc2b[2], acc2b[3]) };

    f32x4 acc3 = C.bias3;
    acc3 = __builtin_amdgcn_mfma_f32_16x16x32_f16(C.w3f, uh2.v, acc3, 0,0,0);

    // carry = sigmoid(c0-c1) = 1/(1+2^-z), z = (c0-c1)*log2e in acc3[3] (local!)
    carry = 1.0f / (1.0f + exp2f(-acc3[3]));
    return acc3;
}

// Flush 4 staged steps. q<3: 12B digit chunk per step; q3: d9 + carry pair.
static __device__ __forceinline__ void flush4(char* outc, int q,
                                              unsigned dbq, unsigned cbq,
                                              const f32x4& g0, const f32x4& g1,
                                              const f32x4& g2, const f32x4& g3)
{
    if (q < 3){
        *(f32x3u*)(outc + dbq +   0) = f32x3u{g0[0], g0[1], g0[2]};
        *(f32x3u*)(outc + dbq +  40) = f32x3u{g1[0], g1[1], g1[2]};
        *(f32x3u*)(outc + dbq +  80) = f32x3u{g2[0], g2[1], g2[2]};
        *(f32x3u*)(outc + dbq + 120) = f32x3u{g3[0], g3[1], g3[2]};
    } else {
        *(float*)(outc + dbq +   0) = g0[0];
        *(float*)(outc + dbq +  40) = g1[0];
        *(float*)(outc + dbq +  80) = g2[0];
        *(float*)(outc + dbq + 120) = g3[0];
        *(float2*)(outc + cbq +  0) = float2{g0[1], g0[2]};
        *(float2*)(outc + cbq +  8) = float2{g1[1], g1[2]};
        *(float2*)(outc + cbq + 16) = float2{g2[1], g2[2]};
        *(float2*)(outc + cbq + 24) = float2{g3[1], g3[2]};
    }
}

__global__ __launch_bounds__(256, 4)
void mlp_mfma_kernel(const int* __restrict__ a, const int* __restrict__ b,
                     const float* __restrict__ Ea, const float* __restrict__ Eb,
                     const float* __restrict__ W1, const float* __restrict__ b1,
                     const float* __restrict__ W2, const float* __restrict__ b2,
                     const float* __restrict__ Wd, const float* __restrict__ bd,
                     const float* __restrict__ Wc, const float* __restrict__ bc,
                     float* __restrict__ out)
{
    __shared__ __attribute__((aligned(16))) _Float16 Pab[100*72];
    __shared__ __attribute__((aligned(8))) unsigned char pkT[64*72]; // [sample][step]

    const int tid = threadIdx.x;
    const int wv  = tid >> 6;
    const int l   = tid & 63;
    const int q   = l >> 4;        // lane quad: k-group for A/B frags, row-group for C
    const int n   = l & 15;        // sample (col) within wave / row within A

    const int sBase = blockIdx.x * 64;

    // ---- stage digits: coalesced int4 loads -> packed dwords pkT[sample][step] ----
    {
        const i32x4* ap = (const i32x4*)(a + (size_t)sBase * LSEQ);
        const i32x4* bp = (const i32x4*)(b + (size_t)sBase * LSEQ);
        #pragma unroll
        for (int k = 0; k < 4; k++){
            int v = tid + k*256;
            i32x4 av = ap[v], bv = bp[v];
            int ns = v >> 4, s0 = (v & 15) << 2;
            unsigned pk = (unsigned)(av[0]*10 + bv[0])
                        | ((unsigned)(av[1]*10 + bv[1]) << 8)
                        | ((unsigned)(av[2]*10 + bv[2]) << 16)
                        | ((unsigned)(av[3]*10 + bv[3]) << 24);
            *(unsigned*)&pkT[ns*72 + s0] = pk;
        }
    }

    // ---- layer-1 table (f16): Pab[p][j] = b1[j] + W1[j][17] + Ea[p/10]·W1[j][0:8] + Eb[p%10]·W1[j][8:16]
    for (int e = tid; e < 6400; e += 256){
        int p = e >> 6, j = e & 63;
        int da = p / 10, db = p - da*10;
        float acc = b1[j] + W1[j*18 + 17];
        #pragma unroll
        for (int k2 = 0; k2 < 8; k2++){
            acc = fmaf(Ea[da*8 + k2], W1[j*18 + k2],     acc);
            acc = fmaf(Eb[db*8 + k2], W1[j*18 + 8 + k2], acc);
        }
        Pab[p*72 + j] = (_Float16)acc;
    }

    // ---- per-lane constants (named f16 frags) ----
    StepCtx C;
    C.Pab = Pab; C.q = q;
    {
        union { half8 v; _Float16 e[8]; } ud;
        #pragma unroll
        for (int jj = 0; jj < 8; jj++) ud.e[jj] = (_Float16)(W1[(q*8+jj)*18 + 16] - W1[(q*8+jj)*18 + 17]);
        C.dcr0 = ud.v;
        #pragma unroll
        for (int jj = 0; jj < 8; jj++) ud.e[jj] = (_Float16)(W1[(32+q*8+jj)*18 + 16] - W1[(32+q*8+jj)*18 + 17]);
        C.dcr1 = ud.v;
    }

    // W2 A-frags with PERMUTED rows: lane row n covers W2 rows 8*(n>>2)+(n&3)
    // (+4 for tile b) so C-slots give h2 rows 8q..8q+7 in-lane.
    {
        union { half8 v; _Float16 e[8]; } uw;
        const int r0 = ((n >> 2) << 3) + (n & 3);      // tile a
        const int r1 = r0 + 4;                         // tile b
        #pragma unroll
        for (int jj = 0; jj < 8; jj++) uw.e[jj] = (_Float16)W2[r0*64 +      q*8 + jj];
        C.w2f00 = uw.v;
        #pragma unroll
        for (int jj = 0; jj < 8; jj++) uw.e[jj] = (_Float16)W2[r0*64 + 32 + q*8 + jj];
        C.w2f01 = uw.v;
        #pragma unroll
        for (int jj = 0; jj < 8; jj++) uw.e[jj] = (_Float16)W2[r1*64 +      q*8 + jj];
        C.w2f10 = uw.v;
        #pragma unroll
        for (int jj = 0; jj < 8; jj++) uw.e[jj] = (_Float16)W2[r1*64 + 32 + q*8 + jj];
        C.w2f11 = uw.v;
    }

    // W3 A-frag, remapped rows: quad qm = n>>2, slot gm = n&3.
    //   qm<3 : gm<3 -> Wd[qm*3+gm], gm==3 -> DIFF
    //   qm==3: gm==0 -> Wd[9], gm==1 -> Wc[0], gm==2 -> Wc[1], gm==3 -> DIFF
    // DIFF[k] = (Wc[0][k]-Wc[1][k])*log2e
    {
        union { half8 v; _Float16 e[8]; } u3;
        const int qm = n >> 2, gm = n & 3;
        #pragma unroll
        for (int jj = 0; jj < 8; jj++){
            int k = q*8 + jj;
            float x;
            if (gm == 3)      x = (Wc[k] - Wc[32+k]) * LOG2E;
            else if (qm < 3)  x = Wd[(qm*3+gm)*32 + k];
            else if (gm == 0) x = Wd[9*32 + k];
            else              x = Wc[(gm-1)*32 + k];
            u3.e[jj] = (_Float16)x;
        }
        C.w3f = u3.v;
    }

    // permuted biases
    C.bias2a = f32x4{ b2[8*q+0], b2[8*q+1], b2[8*q+2], b2[8*q+3] };
    C.bias2b = f32x4{ b2[8*q+4], b2[8*q+5], b2[8*q+6], b2[8*q+7] };
    {
        const float diffB = (bc[0] - bc[1]) * LOG2E;
        float t0, t1, t2;
        if (q < 3){ t0 = bd[q*3+0]; t1 = bd[q*3+1]; t2 = bd[q*3+2]; }
        else      { t0 = bd[9];     t1 = bc[0];     t2 = bc[1];     }
        C.bias3 = f32x4{t0, t1, t2, diffB};
    }

    __syncthreads();

    const int tn = sBase + wv*16 + n;            // this lane's sample
    const int lc = wv*16 + n;                    // pkT row
    char* outc = (char*)out;
    const unsigned dbase = (unsigned)tn*2560u + (unsigned)q*12u;       // digit section, bytes
    const unsigned cbase = (unsigned)(NBATCH*(size_t)LSEQ*10*4) + (unsigned)tn*512u; // carry sect

    float carry = 1.0f;
    int c0, c1;                                  // current 8-step idx bytes
    half8 PAa0, PAa1, PAb0, PAb1;                // named ping-pong Pab rows
    {
        int2 cc = *(const int2*)&pkT[lc*72];
        c0 = cc.x; c1 = cc.y;
        const _Float16* r0 = &Pab[(c0 & 255)*72 + q*8];
        PAa0 = *(const half8*)r0;
        PAa1 = *(const half8*)(r0 + 32);
    }

    for (int so = 0; so < LSEQ; so += 8){
        // next block's idx bytes (last block: re-read own block; value unused)
        int2 nd = *(const int2*)&pkT[lc*72 + (so < 56 ? so + 8 : so)];

        f32x4 g0, g1, g2, g3;
        // steps so+0 .. so+3 (prefetch bytes 1..4 of this block)
        g0 = step_fn(C, carry, PAa0, PAa1, PAb0, PAb1, c0 >> 8);
        g1 = step_fn(C, carry, PAb0, PAb1, PAa0, PAa1, c0 >> 16);
        g2 = step_fn(C, carry, PAa0, PAa1, PAb0, PAb1, c0 >> 24);
        g3 = step_fn(C, carry, PAb0, PAb1, PAa0, PAa1, c1);
        flush4(outc, q, dbase + (unsigned)so*40u, cbase + (unsigned)so*8u, g0, g1, g2, g3);
        // steps so+4 .. so+7 (prefetch bytes 5..7, then next block's byte 0)
        g0 = step_fn(C, carry, PAa0, PAa1, PAb0, PAb1, c1 >> 8);
        g1 = step_fn(C, carry, PAb0, PAb1, PAa0, PAa1, c1 >> 16);
        g2 = step_fn(C, carry, PAa0, PAa1, PAb0, PAb1, c1 >> 24);
        g3 = step_fn(C, carry, PAb0, PAb1, PAa0, PAa1, nd.x);
        flush4(outc, q, dbase + (unsigned)(so+4)*40u, cbase + (unsigned)(so+4)*8u, g0, g1, g2, g3);

        c0 = nd.x; c1 = nd.y;
    }
}

extern "C" void kernel_launch(void* const* d_in, const int* in_sizes, int n_in,
                              void* d_out, int out_size, void* d_ws, size_t ws_size,
                              hipStream_t stream) {
    const int*   a  = (const int*)d_in[0];
    const int*   b  = (const int*)d_in[1];
    const float* Ea = (const float*)d_in[2];
    const float* Eb = (const float*)d_in[3];
    const float* W1 = (const float*)d_in[4];
    const float* b1 = (const float*)d_in[5];
    const float* W2 = (const float*)d_in[6];
    const float* b2 = (const float*)d_in[7];
    const float* Wd = (const float*)d_in[8];
    const float* bd = (const float*)d_in[9];
    const float* Wc = (const float*)d_in[10];
    const float* bc = (const float*)d_in[11];

    mlp_mfma_kernel<<<NBATCH / 64, 256, 0, stream>>>(a, b, Ea, Eb, W1, b1,
                                                     W2, b2, Wd, bd, Wc, bc,
                                                     (float*)d_out);
}

// Round 10
// 276.849 us; speedup vs baseline: 1.0082x; 1.0082x over previous
//
#include <hip/hip_runtime.h>
#include <hip/hip_bf16.h>
#include <stdint.h>

#define NBATCH 65536
#define LSEQ   64

typedef __attribute__((ext_vector_type(8))) _Float16 half8;
typedef __attribute__((ext_vector_type(2))) __fp16  fp16x2; // builtin cvt_pkrtz return type
typedef __attribute__((ext_vector_type(4))) float f32x4;
typedef __attribute__((ext_vector_type(4), aligned(8))) float f32x4u; // 8B-aligned 16B store
typedef __attribute__((ext_vector_type(4))) int   i32x4;

#define LOG2E 1.44269504088896341f

// relu + pack two f32 -> one dword of two f16 (RTZ)
static __device__ __forceinline__ int relu_pk_f16(float x, float y){
    union { fp16x2 h; int i; } u;
    u.h = __builtin_amdgcn_cvt_pkrtz(fmaxf(x, 0.f), fmaxf(y, 0.f));
    return u.i;
}

// 1 wave = 16 samples. Layer1 folded into f16 LDS table + packed-f16 carry FMA.
// Layers 2+3 on MFMA 16x16x32 f16, fp32 accumulate. Block = 4 waves.
// W2 rows PERMUTED so MFMA2's C-layout directly yields the layer-3 B-frag.
// Carry via replicated DIFF row (= (Wc0-Wc1)*log2e in every quad's row 3):
// z lands in acc3[3] of every lane; carry = 1/(1+2^-z) locally.
//
// THIS ROUND: coalesced stores via wave-local LDS staging. Per step each
// lane drops its 3 payload floats into stgD/stgC; every 4 steps the wave
// re-partitions (thread l -> sample l>>2, quarter l&3) and writes the
// sample's 160B step-contiguous digit chunk as 16+16+8B pieces + dwordx4
// carry. Store insts per wave per 4 steps: ~10 -> 4; piece size 12B -> 16B.
// stgD row stride 41 dwords => write bank map (9n+3q) is <=2-way (free).

struct StepCtx {
    half8 dcr0, dcr1, w2f00, w2f01, w2f10, w2f11, w3f;
    f32x4 bias2a, bias2b, bias3;
    const _Float16* Pab;
    int q;
};

// One step: h1 from pc0/pc1, prefetch row for byte ib into pn0/pn1, MFMA x5,
// carry, stage payload into wave-local LDS. u is a compile-time literal.
static __device__ __forceinline__ void step_fn(const StepCtx& C, float& carry,
                                               const half8& pc0, const half8& pc1,
                                               half8& pn0, half8& pn1, int ib,
                                               float* sdq, float* scq, bool isq3, int u)
{
    _Float16 ch = (_Float16)carry;
    half8 c8 = {ch,ch,ch,ch,ch,ch,ch,ch};
    half8 z  = {};
    half8 h10 = __builtin_elementwise_max(pc0 + c8*C.dcr0, z);
    half8 h11 = __builtin_elementwise_max(pc1 + c8*C.dcr1, z);

    const _Float16* rn = C.Pab + (ib & 255)*72 + C.q*8;
    pn0 = *(const half8*)rn;
    pn1 = *(const half8*)(rn + 32);

    f32x4 acc2a = C.bias2a, acc2b = C.bias2b;
    acc2a = __builtin_amdgcn_mfma_f32_16x16x32_f16(C.w2f00, h10, acc2a, 0,0,0);
    acc2a = __builtin_amdgcn_mfma_f32_16x16x32_f16(C.w2f01, h11, acc2a, 0,0,0);
    acc2b = __builtin_amdgcn_mfma_f32_16x16x32_f16(C.w2f10, h10, acc2b, 0,0,0);
    acc2b = __builtin_amdgcn_mfma_f32_16x16x32_f16(C.w2f11, h11, acc2b, 0,0,0);

    union { i32x4 d; half8 v; } uh2;
    uh2.d = i32x4{ relu_pk_f16(acc2a[0], acc2a[1]), relu_pk_f16(acc2a[2], acc2a[3]),
                   relu_pk_f16(acc2b[0], acc2b[1]), relu_pk_f16(acc2b[2], acc2b[3]) };

    f32x4 acc3 = C.bias3;
    acc3 = __builtin_amdgcn_mfma_f32_16x16x32_f16(C.w3f, uh2.v, acc3, 0,0,0);

    // carry = sigmoid(c0-c1) = 1/(1+2^-z), z = (c0-c1)*log2e in acc3[3] (local)
    carry = 1.0f / (1.0f + exp2f(-acc3[3]));

    // stage payload: slots q*3..q*3+2 (q<3) or {digit slot 9, carry pair} (q3)
    sdq[u*10] = acc3[0];
    if (!isq3){
        sdq[u*10 + 1] = acc3[1];
        sdq[u*10 + 2] = acc3[2];
    } else {
        scq[u*2 + 0] = acc3[1];
        scq[u*2 + 1] = acc3[2];
    }
}

// Wave-local flush of 4 staged steps: thread l -> sample m=l>>2, quarter p=l&3
// writes bytes [p*40, p*40+40) of the sample's 160B contiguous digit chunk.
static __device__ __forceinline__ void flush4(const float* sdw, const float* scw,
                                              int l, char* outc,
                                              unsigned dB, unsigned cB, int so4)
{
    __builtin_amdgcn_wave_barrier();             // reads after this chunk's writes
    {
        const int m = l >> 2, p = l & 3;
        const float* src = sdw + m*41 + p*10;
        char* dst = outc + dB + (unsigned)m*2560u + (unsigned)so4*40u + (unsigned)p*40u;
        f32x4 A = { src[0], src[1], src[2], src[3] };
        f32x4 B = { src[4], src[5], src[6], src[7] };
        float2 Cc = { src[8], src[9] };
        *(f32x4u*)(dst)      = A;
        *(f32x4u*)(dst + 16) = B;
        *(float2*)(dst + 32) = Cc;
    }
    if (l < 32){
        const int m = l >> 1, h = l & 1;
        const float* src = scw + m*9 + h*4;
        char* dst = outc + cB + (unsigned)m*512u + (unsigned)so4*8u + (unsigned)h*16u;
        *(f32x4u*)dst = f32x4{ src[0], src[1], src[2], src[3] };
    }
    __builtin_amdgcn_wave_barrier();             // next chunk's writes after reads
}

__global__ __launch_bounds__(256, 4)
void mlp_mfma_kernel(const int* __restrict__ a, const int* __restrict__ b,
                     const float* __restrict__ Ea, const float* __restrict__ Eb,
                     const float* __restrict__ W1, const float* __restrict__ b1,
                     const float* __restrict__ W2, const float* __restrict__ b2,
                     const float* __restrict__ Wd, const float* __restrict__ bd,
                     const float* __restrict__ Wc, const float* __restrict__ bc,
                     float* __restrict__ out)
{
    __shared__ __attribute__((aligned(16))) _Float16 Pab[100*72];
    __shared__ __attribute__((aligned(8))) unsigned char pkT[64*72]; // [sample][step]
    __shared__ float stgD[4*16*41];   // per-wave digit staging, padded stride 41
    __shared__ float stgC[4*16*9];    // per-wave carry staging, padded stride 9

    const int tid = threadIdx.x;
    const int wv  = tid >> 6;
    const int l   = tid & 63;
    const int q   = l >> 4;        // lane quad: k-group for A/B frags, row-group for C
    const int n   = l & 15;        // sample (col) within wave / row within A

    const int sBase = blockIdx.x * 64;

    // ---- stage digits: coalesced int4 loads -> packed dwords pkT[sample][step] ----
    {
        const i32x4* ap = (const i32x4*)(a + (size_t)sBase * LSEQ);
        const i32x4* bp = (const i32x4*)(b + (size_t)sBase * LSEQ);
        #pragma unroll
        for (int k = 0; k < 4; k++){
            int v = tid + k*256;
            i32x4 av = ap[v], bv = bp[v];
            int ns = v >> 4, s0 = (v & 15) << 2;
            unsigned pk = (unsigned)(av[0]*10 + bv[0])
                        | ((unsigned)(av[1]*10 + bv[1]) << 8)
                        | ((unsigned)(av[2]*10 + bv[2]) << 16)
                        | ((unsigned)(av[3]*10 + bv[3]) << 24);
            *(unsigned*)&pkT[ns*72 + s0] = pk;
        }
    }

    // ---- layer-1 table (f16): Pab[p][j] = b1[j] + W1[j][17] + Ea[p/10]·W1[j][0:8] + Eb[p%10]·W1[j][8:16]
    for (int e = tid; e < 6400; e += 256){
        int p = e >> 6, j = e & 63;
        int da = p / 10, db = p - da*10;
        float acc = b1[j] + W1[j*18 + 17];
        #pragma unroll
        for (int k2 = 0; k2 < 8; k2++){
            acc = fmaf(Ea[da*8 + k2], W1[j*18 + k2],     acc);
            acc = fmaf(Eb[db*8 + k2], W1[j*18 + 8 + k2], acc);
        }
        Pab[p*72 + j] = (_Float16)acc;
    }

    // ---- per-lane constants (named f16 frags) ----
    StepCtx C;
    C.Pab = Pab; C.q = q;
    {
        union { half8 v; _Float16 e[8]; } ud;
        #pragma unroll
        for (int jj = 0; jj < 8; jj++) ud.e[jj] = (_Float16)(W1[(q*8+jj)*18 + 16] - W1[(q*8+jj)*18 + 17]);
        C.dcr0 = ud.v;
        #pragma unroll
        for (int jj = 0; jj < 8; jj++) ud.e[jj] = (_Float16)(W1[(32+q*8+jj)*18 + 16] - W1[(32+q*8+jj)*18 + 17]);
        C.dcr1 = ud.v;
    }

    // W2 A-frags with PERMUTED rows: lane row n covers W2 rows 8*(n>>2)+(n&3)
    // (+4 for tile b) so C-slots give h2 rows 8q..8q+7 in-lane.
    {
        union { half8 v; _Float16 e[8]; } uw;
        const int r0 = ((n >> 2) << 3) + (n & 3);      // tile a
        const int r1 = r0 + 4;                         // tile b
        #pragma unroll
        for (int jj = 0; jj < 8; jj++) uw.e[jj] = (_Float16)W2[r0*64 +      q*8 + jj];
        C.w2f00 = uw.v;
        #pragma unroll
        for (int jj = 0; jj < 8; jj++) uw.e[jj] = (_Float16)W2[r0*64 + 32 + q*8 + jj];
        C.w2f01 = uw.v;
        #pragma unroll
        for (int jj = 0; jj < 8; jj++) uw.e[jj] = (_Float16)W2[r1*64 +      q*8 + jj];
        C.w2f10 = uw.v;
        #pragma unroll
        for (int jj = 0; jj < 8; jj++) uw.e[jj] = (_Float16)W2[r1*64 + 32 + q*8 + jj];
        C.w2f11 = uw.v;
    }

    // W3 A-frag, remapped rows: quad qm = n>>2, slot gm = n&3.
    //   qm<3 : gm<3 -> Wd[qm*3+gm], gm==3 -> DIFF
    //   qm==3: gm==0 -> Wd[9], gm==1 -> Wc[0], gm==2 -> Wc[1], gm==3 -> DIFF
    // DIFF[k] = (Wc[0][k]-Wc[1][k])*log2e
    {
        union { half8 v; _Float16 e[8]; } u3;
        const int qm = n >> 2, gm = n & 3;
        #pragma unroll
        for (int jj = 0; jj < 8; jj++){
            int k = q*8 + jj;
            float x;
            if (gm == 3)      x = (Wc[k] - Wc[32+k]) * LOG2E;
            else if (qm < 3)  x = Wd[(qm*3+gm)*32 + k];
            else if (gm == 0) x = Wd[9*32 + k];
            else              x = Wc[(gm-1)*32 + k];
            u3.e[jj] = (_Float16)x;
        }
        C.w3f = u3.v;
    }

    // permuted biases
    C.bias2a = f32x4{ b2[8*q+0], b2[8*q+1], b2[8*q+2], b2[8*q+3] };
    C.bias2b = f32x4{ b2[8*q+4], b2[8*q+5], b2[8*q+6], b2[8*q+7] };
    {
        const float diffB = (bc[0] - bc[1]) * LOG2E;
        float t0, t1, t2;
        if (q < 3){ t0 = bd[q*3+0]; t1 = bd[q*3+1]; t2 = bd[q*3+2]; }
        else      { t0 = bd[9];     t1 = bc[0];     t2 = bc[1];     }
        C.bias3 = f32x4{t0, t1, t2, diffB};
    }

    __syncthreads();

    const int lc = wv*16 + n;                    // pkT row
    char* outc = (char*)out;
    // wave-local staging pointers
    float* sdw = stgD + wv*(16*41);
    float* scw = stgC + wv*(16*9);
    float* sdq = sdw + n*41 + (q < 3 ? q*3 : 9); // this lane's digit slot base
    float* scq = scw + n*9;                      // this lane's carry slots (q3 only)
    const bool isq3 = (q == 3);
    // wave-level output bases
    const unsigned dB = (unsigned)(sBase + wv*16)*2560u;
    const unsigned cB = (unsigned)(NBATCH*(size_t)LSEQ*10*4) + (unsigned)(sBase + wv*16)*512u;

    float carry = 1.0f;
    int c0, c1;                                  // current 8-step idx bytes
    half8 PAa0, PAa1, PAb0, PAb1;                // named ping-pong Pab rows
    {
        int2 cc = *(const int2*)&pkT[lc*72];
        c0 = cc.x; c1 = cc.y;
        const _Float16* r0 = &Pab[(c0 & 255)*72 + q*8];
        PAa0 = *(const half8*)r0;
        PAa1 = *(const half8*)(r0 + 32);
    }

    for (int so = 0; so < LSEQ; so += 8){
        // next block's idx bytes (last block: re-read own block; value unused)
        int2 nd = *(const int2*)&pkT[lc*72 + (so < 56 ? so + 8 : so)];

        // steps so+0 .. so+3 (prefetch bytes 1..4 of this block)
        step_fn(C, carry, PAa0, PAa1, PAb0, PAb1, c0 >> 8,  sdq, scq, isq3, 0);
        step_fn(C, carry, PAb0, PAb1, PAa0, PAa1, c0 >> 16, sdq, scq, isq3, 1);
        step_fn(C, carry, PAa0, PAa1, PAb0, PAb1, c0 >> 24, sdq, scq, isq3, 2);
        step_fn(C, carry, PAb0, PAb1, PAa0, PAa1, c1,       sdq, scq, isq3, 3);
        flush4(sdw, scw, l, outc, dB, cB, so);
        // steps so+4 .. so+7 (prefetch bytes 5..7, then next block's byte 0)
        step_fn(C, carry, PAa0, PAa1, PAb0, PAb1, c1 >> 8,  sdq, scq, isq3, 0);
        step_fn(C, carry, PAb0, PAb1, PAa0, PAa1, c1 >> 16, sdq, scq, isq3, 1);
        step_fn(C, carry, PAa0, PAa1, PAb0, PAb1, c1 >> 24, sdq, scq, isq3, 2);
        step_fn(C, carry, PAb0, PAb1, PAa0, PAa1, nd.x,     sdq, scq, isq3, 3);
        flush4(sdw, scw, l, outc, dB, cB, so + 4);

        c0 = nd.x; c1 = nd.y;
    }
}

extern "C" void kernel_launch(void* const* d_in, const int* in_sizes, int n_in,
                              void* d_out, int out_size, void* d_ws, size_t ws_size,
                              hipStream_t stream) {
    const int*   a  = (const int*)d_in[0];
    const int*   b  = (const int*)d_in[1];
    const float* Ea = (const float*)d_in[2];
    const float* Eb = (const float*)d_in[3];
    const float* W1 = (const float*)d_in[4];
    const float* b1 = (const float*)d_in[5];
    const float* W2 = (const float*)d_in[6];
    const float* b2 = (const float*)d_in[7];
    const float* Wd = (const float*)d_in[8];
    const float* bd = (const float*)d_in[9];
    const float* Wc = (const float*)d_in[10];
    const float* bc = (const float*)d_in[11];

    mlp_mfma_kernel<<<NBATCH / 64, 256, 0, stream>>>(a, b, Ea, Eb, W1, b1,
                                                     W2, b2, Wd, bd, Wc, bc,
                                                     (float*)d_out);
}